// Round 1
// baseline (273.496 us; speedup 1.0000x reference)
//
#include <hip/hip_runtime.h>
#include <hip/hip_bf16.h>
#include <math.h>

// Problem constants (B,C_IN,C_OUT,STYLE,H,W = 4,128,128,512,64,64)
#define BB 4
#define CIN 128
#define COUT 128
#define NSTYLE 512
#define HH 64
#define WW 64
#define NN 4096        // H*W
#define CQK 16
#define EPSV 1e-5f

// ---- workspace layout (float offsets) ----
static constexpr size_t OFF_SCALE = 0;                       // [4*128]
static constexpr size_t OFF_BIAS  = 512;                     // [4*128]
static constexpr size_t OFF_H     = 1024;                    // [4*128*4096]
static constexpr size_t OFF_Q     = OFF_H  + (size_t)BB*COUT*NN;   // [4*16*4096]
static constexpr size_t OFF_K     = OFF_Q  + (size_t)BB*CQK*NN;
static constexpr size_t OFF_V     = OFF_K  + (size_t)BB*CQK*NN;    // [4*128*4096]
static constexpr size_t OFF_AO    = OFF_V  + (size_t)BB*COUT*NN;   // [4*128*4096]

// ---------------------------------------------------------------------------
// k1: scale[b,c] = style[b]·ss_w[c] + ss_b[c]; bias likewise. 1 wave / (b,c).
// ---------------------------------------------------------------------------
__global__ __launch_bounds__(64)
void style_affine(const float* __restrict__ style,
                  const float* __restrict__ ss_w, const float* __restrict__ ss_b,
                  const float* __restrict__ sb_w, const float* __restrict__ sb_b,
                  float* __restrict__ ws) {
    int bc = blockIdx.x;            // b*128 + c
    int b = bc >> 7, c = bc & 127;
    int lane = threadIdx.x;         // 0..63
    const float* st = style + (size_t)b * NSTYLE;
    float s1 = 0.f, s2 = 0.f;
    for (int e = lane; e < NSTYLE; e += 64) {
        float sv = st[e];
        s1 += sv * ss_w[(size_t)c * NSTYLE + e];
        s2 += sv * sb_w[(size_t)c * NSTYLE + e];
    }
    #pragma unroll
    for (int off = 32; off; off >>= 1) {
        s1 += __shfl_xor(s1, off);
        s2 += __shfl_xor(s2, off);
    }
    if (lane == 0) {
        ws[OFF_SCALE + bc] = s1 + ss_b[c];
        ws[OFF_BIAS  + bc] = s2 + sb_b[c];
    }
}

// ---------------------------------------------------------------------------
// k2: conv3x3 (pad 1) + bias + AdaIN modulation -> h in ws.
// Block: 256 thr, spatial tile 32x8, 16 output channels, LDS-staged input
// (8 ci at a time), weights via block-uniform (scalar) loads.
// Grid: (16 spatial tiles, 8 co-groups, 4 batch) = 512 blocks.
// ---------------------------------------------------------------------------
__global__ __launch_bounds__(256)
void conv_mod(const float* __restrict__ x,
              const float* __restrict__ conv_w,
              const float* __restrict__ conv_b,
              const float* __restrict__ ws,
              float* __restrict__ hout) {
    const int b   = blockIdx.z;
    const int co0 = blockIdx.y * 16;
    const int tx0 = (blockIdx.x & 1) * 32;
    const int ty0 = (blockIdx.x >> 1) * 8;
    const int t  = threadIdx.x;
    const int lx = t & 31;
    const int ly = t >> 5;

    __shared__ float s_in[8][10][34];   // 10.9 KB

    float acc[16];
    #pragma unroll
    for (int i = 0; i < 16; ++i) acc[i] = 0.f;

    const float* xb = x + (size_t)b * CIN * NN;

    for (int cb = 0; cb < 16; ++cb) {           // 16 chunks of 8 input channels
        __syncthreads();                        // protect previous chunk's reads
        // stage 8 x (10 x 34) input halo tile
        for (int idx = t; idx < 8 * 340; idx += 256) {
            int cc  = idx / 340;
            int rem = idx - cc * 340;
            int r   = rem / 34;
            int cx  = rem - r * 34;
            int gy  = ty0 + r - 1;
            int gx  = tx0 + cx - 1;
            float v = 0.f;
            if ((unsigned)gy < 64u && (unsigned)gx < 64u)
                v = xb[(size_t)(cb * 8 + cc) * NN + gy * 64 + gx];
            s_in[cc][r][cx] = v;
        }
        __syncthreads();

        for (int cc = 0; cc < 8; ++cc) {
            const int ci = cb * 8 + cc;
            float tap[9];
            #pragma unroll
            for (int ky = 0; ky < 3; ++ky)
                #pragma unroll
                for (int kx = 0; kx < 3; ++kx)
                    tap[ky * 3 + kx] = s_in[cc][ly + ky][lx + kx];
            #pragma unroll
            for (int u = 0; u < 16; ++u) {
                const float* wp = conv_w + ((size_t)(co0 + u) * CIN + ci) * 9;
                float a = acc[u];
                a += tap[0] * wp[0]; a += tap[1] * wp[1]; a += tap[2] * wp[2];
                a += tap[3] * wp[3]; a += tap[4] * wp[4]; a += tap[5] * wp[5];
                a += tap[6] * wp[6]; a += tap[7] * wp[7]; a += tap[8] * wp[8];
                acc[u] = a;
            }
        }
    }

    const int gy = ty0 + ly, gx = tx0 + lx;
    #pragma unroll
    for (int u = 0; u < 16; ++u) {
        const int co = co0 + u;
        const float sc = ws[OFF_SCALE + b * 128 + co];
        const float bi = ws[OFF_BIAS  + b * 128 + co];
        float v = (acc[u] + conv_b[co]) * (1.f + sc) + bi;
        hout[(size_t)(b * 128 + co) * NN + gy * 64 + gx] = v;
    }
}

// ---------------------------------------------------------------------------
// k3 (runs only if gamma != 0): q/k/v 1x1 convs from h. One block per
// (b, output-channel); simple but correct.
// ---------------------------------------------------------------------------
__global__ __launch_bounds__(256)
void qkv_kernel(float* __restrict__ ws,
                const float* __restrict__ qw, const float* __restrict__ qb,
                const float* __restrict__ kw, const float* __restrict__ kb,
                const float* __restrict__ vw, const float* __restrict__ vb,
                const float* __restrict__ gamma) {
    if (gamma[0] == 0.f) return;
    const int b  = blockIdx.y;
    const int oc = blockIdx.x;   // 0..159: 16 q, 16 k, 128 v
    const float* wrow; float bias; float* dst;
    if (oc < 16)      { wrow = qw + (size_t)oc * 128;        bias = qb[oc];
                        dst = ws + OFF_Q + (size_t)(b * 16 + oc) * NN; }
    else if (oc < 32) { int c = oc - 16; wrow = kw + (size_t)c * 128; bias = kb[c];
                        dst = ws + OFF_K + (size_t)(b * 16 + c) * NN; }
    else              { int c = oc - 32; wrow = vw + (size_t)c * 128; bias = vb[c];
                        dst = ws + OFF_V + (size_t)(b * 128 + c) * NN; }
    const float* hb = ws + OFF_H + (size_t)b * 128 * NN;
    for (int n = threadIdx.x; n < NN; n += 256) {
        float a = bias;
        for (int ci = 0; ci < 128; ++ci) a += hb[(size_t)ci * NN + n] * wrow[ci];
        dst[n] = a;
    }
}

// ---------------------------------------------------------------------------
// k4 (runs only if gamma != 0): flash-style attention, 64 queries per block,
// online softmax, no NxN materialization.
//   attn[b,n,m] = softmax_m(q[:,n]·k[:,m]);  out[b,c,n] = sum_m v[c,m]*attn[n,m]
// ---------------------------------------------------------------------------
__global__ __launch_bounds__(256)
void attn_kernel(float* __restrict__ ws, const float* __restrict__ gamma) {
    if (gamma[0] == 0.f) return;
    const int b  = blockIdx.y;
    const int n0 = blockIdx.x * 64;
    const int t  = threadIdx.x;

    __shared__ float q_s[16][64];
    __shared__ float k_s[16][64];
    __shared__ float v_s[64][129];   // padded: conflict-free transposed access
    __shared__ float p_s[64][65];
    __shared__ float m_run[64], l_run[64], sc_s[64];

    const float* qp = ws + OFF_Q + (size_t)b * 16 * NN;
    const float* kp = ws + OFF_K + (size_t)b * 16 * NN;
    const float* vp = ws + OFF_V + (size_t)b * 128 * NN;

    for (int idx = t; idx < 16 * 64; idx += 256) {
        int cq = idx >> 6, j = idx & 63;
        q_s[cq][j] = qp[(size_t)cq * NN + n0 + j];
    }
    if (t < 64) { m_run[t] = -1e30f; l_run[t] = 0.f; }

    const int n  = t & 63;     // query within tile
    const int cg = t >> 6;     // channel group: c in [cg*32, cg*32+32)
    float acc[32];
    #pragma unroll
    for (int i = 0; i < 32; ++i) acc[i] = 0.f;
    __syncthreads();

    for (int mt = 0; mt < 64; ++mt) {
        const int m0 = mt * 64;
        for (int idx = t; idx < 16 * 64; idx += 256) {
            int cq = idx >> 6, j = idx & 63;
            k_s[cq][j] = kp[(size_t)cq * NN + m0 + j];
        }
        for (int idx = t; idx < 128 * 64; idx += 256) {
            int c = idx >> 6, j = idx & 63;
            v_s[j][c] = vp[(size_t)c * NN + m0 + j];
        }
        __syncthreads();
        // scores: thread -> (n, 16 consecutive m)
        {
            const int nn2   = t & 63;
            const int mbase = (t >> 6) * 16;
            for (int mi = 0; mi < 16; ++mi) {
                const int mm = mbase + mi;
                float s = 0.f;
                #pragma unroll
                for (int cq = 0; cq < 16; ++cq) s += q_s[cq][nn2] * k_s[cq][mm];
                p_s[nn2][mm] = s;
            }
        }
        __syncthreads();
        // online softmax per row (64 rows by 64 threads)
        if (t < 64) {
            float mold = m_run[t];
            float mx = mold;
            for (int mm = 0; mm < 64; ++mm) mx = fmaxf(mx, p_s[t][mm]);
            float sc = expf(mold - mx);
            float rs = 0.f;
            for (int mm = 0; mm < 64; ++mm) {
                float p = expf(p_s[t][mm] - mx);
                p_s[t][mm] = p;
                rs += p;
            }
            l_run[t] = l_run[t] * sc + rs;
            m_run[t] = mx;
            sc_s[t]  = sc;
        }
        __syncthreads();
        // accumulate PV
        {
            const float sc = sc_s[n];
            #pragma unroll
            for (int i = 0; i < 32; ++i) acc[i] *= sc;
            for (int mm = 0; mm < 64; ++mm) {
                const float p = p_s[n][mm];
                #pragma unroll
                for (int i = 0; i < 32; ++i) acc[i] += p * v_s[mm][cg * 32 + i];
            }
        }
        __syncthreads();
    }

    const float inv = 1.f / l_run[n];
    float* ao = ws + OFF_AO + (size_t)b * 128 * NN;
    for (int i = 0; i < 32; ++i)
        ao[(size_t)(cg * 32 + i) * NN + n0 + n] = acc[i] * inv;
}

// ---------------------------------------------------------------------------
// k5: h2 = gamma*attn_out + h; InstanceNorm (biased var, eps=1e-5); LeakyReLU.
// One block per (b,c) plane of 4096; values held in registers (single pass).
// ---------------------------------------------------------------------------
__global__ __launch_bounds__(256)
void inorm_lrelu(const float* __restrict__ ws,
                 const float* __restrict__ gamma,
                 float* __restrict__ out) {
    const int bc = blockIdx.x;      // b*128 + c
    const int t  = threadIdx.x;
    const float g = gamma[0];

    const float4* hp = (const float4*)(ws + OFF_H  + (size_t)bc * NN);
    const float4* ap = (const float4*)(ws + OFF_AO + (size_t)bc * NN);

    float4 v[4];
    #pragma unroll
    for (int i = 0; i < 4; ++i) {
        float4 hv = hp[t + 256 * i];
        if (g != 0.f) {
            float4 av = ap[t + 256 * i];
            hv.x += g * av.x; hv.y += g * av.y; hv.z += g * av.z; hv.w += g * av.w;
        }
        v[i] = hv;
    }

    float s1 = 0.f, s2 = 0.f;
    #pragma unroll
    for (int i = 0; i < 4; ++i) {
        s1 += v[i].x + v[i].y + v[i].z + v[i].w;
        s2 += v[i].x * v[i].x + v[i].y * v[i].y + v[i].z * v[i].z + v[i].w * v[i].w;
    }
    #pragma unroll
    for (int off = 32; off; off >>= 1) {
        s1 += __shfl_xor(s1, off);
        s2 += __shfl_xor(s2, off);
    }
    __shared__ float r1[4], r2[4];
    if ((t & 63) == 0) { r1[t >> 6] = s1; r2[t >> 6] = s2; }
    __syncthreads();
    const float S1 = r1[0] + r1[1] + r1[2] + r1[3];
    const float S2 = r2[0] + r2[1] + r2[2] + r2[3];
    const float mu  = S1 * (1.f / 4096.f);
    const float var = S2 * (1.f / 4096.f) - mu * mu;
    const float rs  = 1.f / sqrtf(var + EPSV);

    float4* op = (float4*)out + (size_t)bc * (NN / 4);
    #pragma unroll
    for (int i = 0; i < 4; ++i) {
        float4 o;
        o.x = (v[i].x - mu) * rs; o.x = o.x >= 0.f ? o.x : 0.2f * o.x;
        o.y = (v[i].y - mu) * rs; o.y = o.y >= 0.f ? o.y : 0.2f * o.y;
        o.z = (v[i].z - mu) * rs; o.z = o.z >= 0.f ? o.z : 0.2f * o.z;
        o.w = (v[i].w - mu) * rs; o.w = o.w >= 0.f ? o.w : 0.2f * o.w;
        op[t + 256 * i] = o;
    }
}

// ---------------------------------------------------------------------------
extern "C" void kernel_launch(void* const* d_in, const int* in_sizes, int n_in,
                              void* d_out, int out_size, void* d_ws, size_t ws_size,
                              hipStream_t stream) {
    const float* x      = (const float*)d_in[0];
    const float* style  = (const float*)d_in[1];
    const float* conv_w = (const float*)d_in[2];
    const float* conv_b = (const float*)d_in[3];
    const float* ss_w   = (const float*)d_in[4];
    const float* ss_b   = (const float*)d_in[5];
    const float* sb_w   = (const float*)d_in[6];
    const float* sb_b   = (const float*)d_in[7];
    const float* q_w    = (const float*)d_in[8];
    const float* q_b    = (const float*)d_in[9];
    const float* k_w    = (const float*)d_in[10];
    const float* k_b    = (const float*)d_in[11];
    const float* v_w    = (const float*)d_in[12];
    const float* v_b    = (const float*)d_in[13];
    const float* gamma  = (const float*)d_in[14];
    float* ws  = (float*)d_ws;
    float* out = (float*)d_out;

    style_affine<<<512, 64, 0, stream>>>(style, ss_w, ss_b, sb_w, sb_b, ws);
    conv_mod<<<dim3(16, 8, 4), 256, 0, stream>>>(x, conv_w, conv_b, ws, ws + OFF_H);
    qkv_kernel<<<dim3(160, 4), 256, 0, stream>>>(ws, q_w, q_b, k_w, k_b, v_w, v_b, gamma);
    attn_kernel<<<dim3(64, 4), 256, 0, stream>>>(ws, gamma);
    inorm_lrelu<<<512, 256, 0, stream>>>(ws, gamma, out);
}

// Round 2
// 249.158 us; speedup vs baseline: 1.0977x; 1.0977x over previous
//
#include <hip/hip_runtime.h>
#include <hip/hip_bf16.h>
#include <math.h>

// Problem constants (B,C_IN,C_OUT,STYLE,H,W = 4,128,128,512,64,64)
#define BB 4
#define CIN 128
#define COUT 128
#define NSTYLE 512
#define HH 64
#define WW 64
#define NN 4096        // H*W
#define CQK 16
#define EPSV 1e-5f

// ---- workspace layout (float offsets) ----
static constexpr size_t OFF_SCALE = 0;                       // [4*128]
static constexpr size_t OFF_BIAS  = 512;                     // [4*128]
static constexpr size_t OFF_H     = 1024;                    // [4*128*4096]
static constexpr size_t OFF_Q     = OFF_H  + (size_t)BB*COUT*NN;   // [4*16*4096]
static constexpr size_t OFF_K     = OFF_Q  + (size_t)BB*CQK*NN;
static constexpr size_t OFF_V     = OFF_K  + (size_t)BB*CQK*NN;    // [4*128*4096]
static constexpr size_t OFF_AO    = OFF_V  + (size_t)BB*COUT*NN;   // [4*128*4096]

// ---------------------------------------------------------------------------
// k1: scale[b,c] = style[b]·ss_w[c] + ss_b[c]; bias likewise. 1 wave / (b,c).
// ---------------------------------------------------------------------------
__global__ __launch_bounds__(64)
void style_affine(const float* __restrict__ style,
                  const float* __restrict__ ss_w, const float* __restrict__ ss_b,
                  const float* __restrict__ sb_w, const float* __restrict__ sb_b,
                  float* __restrict__ ws) {
    int bc = blockIdx.x;            // b*128 + c
    int b = bc >> 7, c = bc & 127;
    int lane = threadIdx.x;         // 0..63
    const float* st = style + (size_t)b * NSTYLE;
    float s1 = 0.f, s2 = 0.f;
    for (int e = lane; e < NSTYLE; e += 64) {
        float sv = st[e];
        s1 += sv * ss_w[(size_t)c * NSTYLE + e];
        s2 += sv * sb_w[(size_t)c * NSTYLE + e];
    }
    #pragma unroll
    for (int off = 32; off; off >>= 1) {
        s1 += __shfl_xor(s1, off);
        s2 += __shfl_xor(s2, off);
    }
    if (lane == 0) {
        ws[OFF_SCALE + bc] = s1 + ss_b[c];
        ws[OFF_BIAS  + bc] = s2 + sb_b[c];
    }
}

// ---------------------------------------------------------------------------
// k2: conv3x3 (pad 1) + bias + AdaIN modulation -> h in ws.
// Block: 256 threads as 16x16; each thread computes a 2x2 pixel block for
// 4 output channels (16 outputs). Tile: 32x32 spatial, 4 co.
// Grid: (4 spatial tiles, 32 co-groups, 4 batch) = 512 blocks.
// Weights: block-uniform scalar loads, double-buffered (wA/wB ping-pong) so
// s_load latency hides under the 144 FMAs of the previous ci.
// Input: LDS-staged per 8-ci chunk, vectorized row staging, b64 tap reads
// at even word offsets (bank-conflict-free).
// ---------------------------------------------------------------------------
struct W36 { float w[36]; };

__device__ __forceinline__ void load_w(float* dst, const float* __restrict__ conv_w,
                                       int co0, int ci) {
    #pragma unroll
    for (int u = 0; u < 4; ++u) {
        const float* wp = conv_w + ((size_t)(co0 + u) * CIN + ci) * 9;
        #pragma unroll
        for (int k = 0; k < 9; ++k) dst[u * 9 + k] = wp[k];
    }
}

__global__ __launch_bounds__(256)
void conv_mod(const float* __restrict__ x,
              const float* __restrict__ conv_w,
              const float* __restrict__ conv_b,
              const float* __restrict__ ws,
              float* __restrict__ hout) {
    const int b   = blockIdx.z;
    const int co0 = blockIdx.y * 4;
    const int tx0 = (blockIdx.x & 1) * 32;       // tile col origin
    const int ty0 = (blockIdx.x >> 1) * 32;      // tile row origin
    const int t   = threadIdx.x;
    const int tx  = t & 15;                      // 0..15
    const int ty  = t >> 4;                      // 0..15

    __shared__ float s_in[8][34][36];            // 39.2 KB, row stride 36 words

    float acc[4][2][2];
    #pragma unroll
    for (int u = 0; u < 4; ++u)
        #pragma unroll
        for (int py = 0; py < 2; ++py)
            #pragma unroll
            for (int px = 0; px < 2; ++px) acc[u][py][px] = 0.f;

    const float* xb = x + (size_t)b * CIN * NN;

    float wA[36], wB[36];
    load_w(wA, conv_w, co0, 0);                  // prologue prefetch (ci=0)

    for (int cb = 0; cb < 16; ++cb) {
        __syncthreads();                         // protect prev chunk's reads
        // ---- stage 8 x (34x34) halo rows; one row per task, vectorized ----
        for (int task = t; task < 272; task += 256) {
            const int cc = task / 34;            // const-div -> magic mul
            const int r  = task - cc * 34;
            const int gy = ty0 + r - 1;
            float* dstrow = &s_in[cc][r][0];
            if ((unsigned)gy < 64u) {
                const float* srow = xb + (size_t)(cb * 8 + cc) * NN + gy * 64;
                dstrow[0] = (tx0 > 0) ? srow[tx0 - 1] : 0.f;
                #pragma unroll
                for (int c = 0; c < 32; c += 4) {
                    float4 v = *reinterpret_cast<const float4*>(srow + tx0 + c);
                    dstrow[1 + c] = v.x; dstrow[2 + c] = v.y;
                    dstrow[3 + c] = v.z; dstrow[4 + c] = v.w;
                }
                dstrow[33] = (tx0 + 32 < 64) ? srow[tx0 + 32] : 0.f;
            } else {
                #pragma unroll
                for (int c = 0; c < 34; ++c) dstrow[c] = 0.f;
            }
        }
        __syncthreads();

        // ---- compute 8 ci, unrolled x2 for weight ping-pong ----
        #pragma unroll
        for (int cc2 = 0; cc2 < 8; cc2 += 2) {
            #pragma unroll
            for (int half = 0; half < 2; ++half) {
                const int cc = cc2 + half;
                const int ci = cb * 8 + cc;
                float* wcur = half ? wB : wA;
                float* wnxt = half ? wA : wB;
                if (ci + 1 < 128) load_w(wnxt, conv_w, co0, ci + 1);

                // taps: rows 2ty..2ty+3, cols 2tx..2tx+3 (b64 pairs, 8B-aligned)
                float tp[4][4];
                #pragma unroll
                for (int dr = 0; dr < 4; ++dr) {
                    float2 a = *reinterpret_cast<const float2*>(&s_in[cc][2 * ty + dr][2 * tx]);
                    float2 c2 = *reinterpret_cast<const float2*>(&s_in[cc][2 * ty + dr][2 * tx + 2]);
                    tp[dr][0] = a.x; tp[dr][1] = a.y; tp[dr][2] = c2.x; tp[dr][3] = c2.y;
                }
                #pragma unroll
                for (int u = 0; u < 4; ++u)
                    #pragma unroll
                    for (int py = 0; py < 2; ++py)
                        #pragma unroll
                        for (int px = 0; px < 2; ++px) {
                            float a = acc[u][py][px];
                            #pragma unroll
                            for (int ky = 0; ky < 3; ++ky)
                                #pragma unroll
                                for (int kx = 0; kx < 3; ++kx)
                                    a += tp[py + ky][px + kx] * wcur[u * 9 + ky * 3 + kx];
                            acc[u][py][px] = a;
                        }
            }
        }
    }

    // ---- epilogue: bias + AdaIN modulation, float2 stores ----
    const int gx0 = tx0 + 2 * tx;
    const int gy0 = ty0 + 2 * ty;
    #pragma unroll
    for (int u = 0; u < 4; ++u) {
        const int co = co0 + u;
        const float sc  = 1.f + ws[OFF_SCALE + b * 128 + co];
        const float bi  = ws[OFF_BIAS  + b * 128 + co];
        const float cbv = conv_b[co];
        float* orow = hout + (size_t)(b * 128 + co) * NN;
        #pragma unroll
        for (int py = 0; py < 2; ++py) {
            float2 o;
            o.x = (acc[u][py][0] + cbv) * sc + bi;
            o.y = (acc[u][py][1] + cbv) * sc + bi;
            *reinterpret_cast<float2*>(orow + (gy0 + py) * 64 + gx0) = o;
        }
    }
}

// ---------------------------------------------------------------------------
// k3 (runs only if gamma != 0): q/k/v 1x1 convs from h. One block per
// (b, output-channel); simple but correct.
// ---------------------------------------------------------------------------
__global__ __launch_bounds__(256)
void qkv_kernel(float* __restrict__ ws,
                const float* __restrict__ qw, const float* __restrict__ qb,
                const float* __restrict__ kw, const float* __restrict__ kb,
                const float* __restrict__ vw, const float* __restrict__ vb,
                const float* __restrict__ gamma) {
    if (gamma[0] == 0.f) return;
    const int b  = blockIdx.y;
    const int oc = blockIdx.x;   // 0..159: 16 q, 16 k, 128 v
    const float* wrow; float bias; float* dst;
    if (oc < 16)      { wrow = qw + (size_t)oc * 128;        bias = qb[oc];
                        dst = ws + OFF_Q + (size_t)(b * 16 + oc) * NN; }
    else if (oc < 32) { int c = oc - 16; wrow = kw + (size_t)c * 128; bias = kb[c];
                        dst = ws + OFF_K + (size_t)(b * 16 + c) * NN; }
    else              { int c = oc - 32; wrow = vw + (size_t)c * 128; bias = vb[c];
                        dst = ws + OFF_V + (size_t)(b * 128 + c) * NN; }
    const float* hb = ws + OFF_H + (size_t)b * 128 * NN;
    for (int n = threadIdx.x; n < NN; n += 256) {
        float a = bias;
        for (int ci = 0; ci < 128; ++ci) a += hb[(size_t)ci * NN + n] * wrow[ci];
        dst[n] = a;
    }
}

// ---------------------------------------------------------------------------
// k4 (runs only if gamma != 0): flash-style attention, 64 queries per block,
// online softmax, no NxN materialization.
// ---------------------------------------------------------------------------
__global__ __launch_bounds__(256)
void attn_kernel(float* __restrict__ ws, const float* __restrict__ gamma) {
    if (gamma[0] == 0.f) return;
    const int b  = blockIdx.y;
    const int n0 = blockIdx.x * 64;
    const int t  = threadIdx.x;

    __shared__ float q_s[16][64];
    __shared__ float k_s[16][64];
    __shared__ float v_s[64][129];
    __shared__ float p_s[64][65];
    __shared__ float m_run[64], l_run[64], sc_s[64];

    const float* qp = ws + OFF_Q + (size_t)b * 16 * NN;
    const float* kp = ws + OFF_K + (size_t)b * 16 * NN;
    const float* vp = ws + OFF_V + (size_t)b * 128 * NN;

    for (int idx = t; idx < 16 * 64; idx += 256) {
        int cq = idx >> 6, j = idx & 63;
        q_s[cq][j] = qp[(size_t)cq * NN + n0 + j];
    }
    if (t < 64) { m_run[t] = -1e30f; l_run[t] = 0.f; }

    const int n  = t & 63;
    const int cg = t >> 6;
    float acc[32];
    #pragma unroll
    for (int i = 0; i < 32; ++i) acc[i] = 0.f;
    __syncthreads();

    for (int mt = 0; mt < 64; ++mt) {
        const int m0 = mt * 64;
        for (int idx = t; idx < 16 * 64; idx += 256) {
            int cq = idx >> 6, j = idx & 63;
            k_s[cq][j] = kp[(size_t)cq * NN + m0 + j];
        }
        for (int idx = t; idx < 128 * 64; idx += 256) {
            int c = idx >> 6, j = idx & 63;
            v_s[j][c] = vp[(size_t)c * NN + m0 + j];
        }
        __syncthreads();
        {
            const int nn2   = t & 63;
            const int mbase = (t >> 6) * 16;
            for (int mi = 0; mi < 16; ++mi) {
                const int mm = mbase + mi;
                float s = 0.f;
                #pragma unroll
                for (int cq = 0; cq < 16; ++cq) s += q_s[cq][nn2] * k_s[cq][mm];
                p_s[nn2][mm] = s;
            }
        }
        __syncthreads();
        if (t < 64) {
            float mold = m_run[t];
            float mx = mold;
            for (int mm = 0; mm < 64; ++mm) mx = fmaxf(mx, p_s[t][mm]);
            float sc = expf(mold - mx);
            float rs = 0.f;
            for (int mm = 0; mm < 64; ++mm) {
                float p = expf(p_s[t][mm] - mx);
                p_s[t][mm] = p;
                rs += p;
            }
            l_run[t] = l_run[t] * sc + rs;
            m_run[t] = mx;
            sc_s[t]  = sc;
        }
        __syncthreads();
        {
            const float sc = sc_s[n];
            #pragma unroll
            for (int i = 0; i < 32; ++i) acc[i] *= sc;
            for (int mm = 0; mm < 64; ++mm) {
                const float p = p_s[n][mm];
                #pragma unroll
                for (int i = 0; i < 32; ++i) acc[i] += p * v_s[mm][cg * 32 + i];
            }
        }
        __syncthreads();
    }

    const float inv = 1.f / l_run[n];
    float* ao = ws + OFF_AO + (size_t)b * 128 * NN;
    for (int i = 0; i < 32; ++i)
        ao[(size_t)(cg * 32 + i) * NN + n0 + n] = acc[i] * inv;
}

// ---------------------------------------------------------------------------
// k5: h2 = gamma*attn_out + h; InstanceNorm (biased var, eps=1e-5); LeakyReLU.
// ---------------------------------------------------------------------------
__global__ __launch_bounds__(256)
void inorm_lrelu(const float* __restrict__ ws,
                 const float* __restrict__ gamma,
                 float* __restrict__ out) {
    const int bc = blockIdx.x;      // b*128 + c
    const int t  = threadIdx.x;
    const float g = gamma[0];

    const float4* hp = (const float4*)(ws + OFF_H  + (size_t)bc * NN);
    const float4* ap = (const float4*)(ws + OFF_AO + (size_t)bc * NN);

    float4 v[4];
    #pragma unroll
    for (int i = 0; i < 4; ++i) {
        float4 hv = hp[t + 256 * i];
        if (g != 0.f) {
            float4 av = ap[t + 256 * i];
            hv.x += g * av.x; hv.y += g * av.y; hv.z += g * av.z; hv.w += g * av.w;
        }
        v[i] = hv;
    }

    float s1 = 0.f, s2 = 0.f;
    #pragma unroll
    for (int i = 0; i < 4; ++i) {
        s1 += v[i].x + v[i].y + v[i].z + v[i].w;
        s2 += v[i].x * v[i].x + v[i].y * v[i].y + v[i].z * v[i].z + v[i].w * v[i].w;
    }
    #pragma unroll
    for (int off = 32; off; off >>= 1) {
        s1 += __shfl_xor(s1, off);
        s2 += __shfl_xor(s2, off);
    }
    __shared__ float r1[4], r2[4];
    if ((t & 63) == 0) { r1[t >> 6] = s1; r2[t >> 6] = s2; }
    __syncthreads();
    const float S1 = r1[0] + r1[1] + r1[2] + r1[3];
    const float S2 = r2[0] + r2[1] + r2[2] + r2[3];
    const float mu  = S1 * (1.f / 4096.f);
    const float var = S2 * (1.f / 4096.f) - mu * mu;
    const float rs  = 1.f / sqrtf(var + EPSV);

    float4* op = (float4*)out + (size_t)bc * (NN / 4);
    #pragma unroll
    for (int i = 0; i < 4; ++i) {
        float4 o;
        o.x = (v[i].x - mu) * rs; o.x = o.x >= 0.f ? o.x : 0.2f * o.x;
        o.y = (v[i].y - mu) * rs; o.y = o.y >= 0.f ? o.y : 0.2f * o.y;
        o.z = (v[i].z - mu) * rs; o.z = o.z >= 0.f ? o.z : 0.2f * o.z;
        o.w = (v[i].w - mu) * rs; o.w = o.w >= 0.f ? o.w : 0.2f * o.w;
        op[t + 256 * i] = o;
    }
}

// ---------------------------------------------------------------------------
extern "C" void kernel_launch(void* const* d_in, const int* in_sizes, int n_in,
                              void* d_out, int out_size, void* d_ws, size_t ws_size,
                              hipStream_t stream) {
    const float* x      = (const float*)d_in[0];
    const float* style  = (const float*)d_in[1];
    const float* conv_w = (const float*)d_in[2];
    const float* conv_b = (const float*)d_in[3];
    const float* ss_w   = (const float*)d_in[4];
    const float* ss_b   = (const float*)d_in[5];
    const float* sb_w   = (const float*)d_in[6];
    const float* sb_b   = (const float*)d_in[7];
    const float* q_w    = (const float*)d_in[8];
    const float* q_b    = (const float*)d_in[9];
    const float* k_w    = (const float*)d_in[10];
    const float* k_b    = (const float*)d_in[11];
    const float* v_w    = (const float*)d_in[12];
    const float* v_b    = (const float*)d_in[13];
    const float* gamma  = (const float*)d_in[14];
    float* ws  = (float*)d_ws;
    float* out = (float*)d_out;

    style_affine<<<512, 64, 0, stream>>>(style, ss_w, ss_b, sb_w, sb_b, ws);
    conv_mod<<<dim3(4, 32, 4), 256, 0, stream>>>(x, conv_w, conv_b, ws, ws + OFF_H);
    qkv_kernel<<<dim3(160, 4), 256, 0, stream>>>(ws, q_w, q_b, k_w, k_b, v_w, v_b, gamma);
    attn_kernel<<<dim3(64, 4), 256, 0, stream>>>(ws, gamma);
    inorm_lrelu<<<512, 256, 0, stream>>>(ws, gamma, out);
}